// Round 14
// baseline (281.348 us; speedup 1.0000x reference)
//
#include <hip/hip_runtime.h>
#include <hip/hip_bf16.h>
#include <math.h>

#define NTOK   16384
#define NEXP   64
#define HID    4096
#define KSEL   8
#define EPS    7.5e-5f
#define NSPLIT 4
#define KSZ    (HID / NSPLIT)

typedef __attribute__((ext_vector_type(8))) short short8;
typedef __attribute__((ext_vector_type(4))) float f32x4;

// d_out element offsets (f32 elements; int outputs stored as float values)
#define O_LOGITS 0u
#define O_PROBS  1048576u
#define O_TIDX   1179648u
#define O_GROUP  1310720u
#define O_IDX    1310784u
#define O_TPE    1441856u
#define O_LB     1441920u
#define O_ZL     1441921u

// ws byte offsets
#define W_CQ      0u          // 512 int: counts[q][e], q = row>>11
#define W_GCOUNT  2048u       // 1 int
#define W_OFFS2   4096u       // 512 int: offsets[e][q]
#define W_LSQP    8192u       // 256 f32 per-block z-loss partials
#define W_LIST    16384u      // 16384 int flagged rows
#define W_PSUM    81920u      // 256*128 f32 per-block half-tile probsum partials
#define W_FLAT    262144u     // 131072 int
#define W_WF      1048576u    // 1 MB: W packed as MFMA B-frags bf16 hi/lo
#define W_PART    2097152u    // NSPLIT x 4 MB f32 partials
#define PART_STRIDE 1048576ull

// round-to-nearest-even f32 -> bf16 bits
__device__ __forceinline__ unsigned short f2bf(float f) {
  unsigned u = __float_as_uint(f);
  return (unsigned short)((u + 0x7fffu + ((u >> 16) & 1u)) >> 16);
}

__device__ __forceinline__ void gload16(const void* g, void* l) {
  __builtin_amdgcn_global_load_lds((const __attribute__((address_space(1))) unsigned int*)g,
                                   (__attribute__((address_space(3))) unsigned int*)l, 16, 0, 0);
}

// ---------------------------------------------------------------------------
// prep: pack W into MFMA B-frags (bf16 hi/lo) + zero counters.
__global__ __launch_bounds__(256) void k_prep(const float* __restrict__ w,
                                              short8* __restrict__ wf,
                                              int* __restrict__ cq,
                                              int* __restrict__ gcount) {
  const int kk   = blockIdx.x;
  const int nb   = threadIdx.x >> 6;
  const int lane = threadIdx.x & 63;
  const int n    = nb * 16 + (lane & 15);
  const int kb   = kk * 32 + (lane >> 4) * 8;
  const float4* wp = (const float4*)(w + (size_t)n * HID + kb);
  float4 f0 = wp[0], f1 = wp[1];
  float fv[8] = {f0.x, f0.y, f0.z, f0.w, f1.x, f1.y, f1.z, f1.w};
  short8 hi, lo;
#pragma unroll
  for (int j = 0; j < 8; ++j) {
    unsigned short h = f2bf(fv[j]);
    hi[j] = (short)h;
    float r = fv[j] - __uint_as_float((unsigned)h << 16);
    lo[j] = (short)f2bf(r);
  }
  size_t base = ((size_t)(kk * 4 + nb) * 2) * 64 + lane;
  wf[base] = hi;
  wf[base + 64] = lo;
  if (blockIdx.x == 0) {
    cq[threadIdx.x] = 0;
    cq[threadIdx.x + 256] = 0;
    if (threadIdx.x == 0) gcount[0] = 0;
  }
}

// ---------------------------------------------------------------------------
// MFMA router GEMM (R8-exact). wf LDS-shared (double-buffered,
// global_load_lds w16, linear frag layout -> conflict-free ds_read_b128);
// x per-lane direct loads; one full __syncthreads per 32-k chunk.
// Launched 3x this round as a timing probe (deterministic, atomics-free).
__global__ __launch_bounds__(256, 4) void k_gemm(const float* __restrict__ x,
                                                 const short8* __restrict__ wf,
                                                 float* __restrict__ part) {
  __shared__ short8 wl[2][512];   // 2 x 8 KB
  const int tid  = threadIdx.x;
  const int wv   = tid >> 6;
  const int lane = tid & 63;
  const int t0   = blockIdx.x * 64;
  const int k0   = blockIdx.y * KSZ;
  const int row  = t0 + wv * 16 + (lane & 15);

  const float* xp = x + (size_t)row * HID + k0 + (lane >> 4) * 8;
  const short8* wbase = wf + (size_t)(k0 >> 5) * 512;

  auto stage = [&](int c, int b) {
    const short8* src = wbase + (size_t)c * 512;
#pragma unroll
    for (int r = 0; r < 2; ++r) {
      const int o = r * 256 + wv * 64;       // wave-uniform LDS base
      gload16(src + o + lane, &wl[b][o]);    // lane*16B added by HW
    }
  };

  f32x4 acc[4] = {{0,0,0,0},{0,0,0,0},{0,0,0,0},{0,0,0,0}};

  stage(0, 0);
  __syncthreads();
  const int nch = KSZ >> 5;   // 32
  for (int c = 0; c < nch; ++c) {
    const int b = c & 1;
    if (c + 1 < nch) stage(c + 1, b ^ 1);

    // x fragment: 8 consecutive f32, split into bf16 hi (trunc) + lo (RNE)
    const float4* xq = (const float4*)(xp + c * 32);
    float4 f0 = xq[0], f1 = xq[1];
    unsigned xb[8] = {__float_as_uint(f0.x), __float_as_uint(f0.y),
                      __float_as_uint(f0.z), __float_as_uint(f0.w),
                      __float_as_uint(f1.x), __float_as_uint(f1.y),
                      __float_as_uint(f1.z), __float_as_uint(f1.w)};
    union { unsigned u[4]; short8 s; } ua, ul;
#pragma unroll
    for (int p = 0; p < 4; ++p) {
      unsigned b0 = xb[2 * p], b1 = xb[2 * p + 1];
      ua.u[p] = __builtin_amdgcn_perm(b1, b0, 0x07060302u);
      float r0 = __uint_as_float(b0) - __uint_as_float(b0 & 0xffff0000u);
      float r1 = __uint_as_float(b1) - __uint_as_float(b1 & 0xffff0000u);
      unsigned t0b = __float_as_uint(r0), t1b = __float_as_uint(r1);
      t0b += 0x7fffu + ((t0b >> 16) & 1u);
      t1b += 0x7fffu + ((t1b >> 16) & 1u);
      ul.u[p] = __builtin_amdgcn_perm(t1b, t0b, 0x07060302u);
    }
    short8 ah = ua.s, al = ul.s;

#pragma unroll
    for (int nb = 0; nb < 4; ++nb) {
      short8 bh = wl[b][nb * 128 + lane];
      short8 bl = wl[b][nb * 128 + 64 + lane];
      acc[nb] = __builtin_amdgcn_mfma_f32_16x16x32_bf16(ah, bh, acc[nb], 0, 0, 0);
      acc[nb] = __builtin_amdgcn_mfma_f32_16x16x32_bf16(al, bh, acc[nb], 0, 0, 0);
      acc[nb] = __builtin_amdgcn_mfma_f32_16x16x32_bf16(ah, bl, acc[nb], 0, 0, 0);
    }
    __syncthreads();   // stage(c+1) landed; all waves done reading wl[b]
  }

  float* p = part + (size_t)blockIdx.y * PART_STRIDE;
  const int mrow = t0 + wv * 16 + (lane >> 4) * 4;
  const int col  = lane & 15;
#pragma unroll
  for (int nb = 0; nb < 4; ++nb)
#pragma unroll
    for (int r = 0; r < 4; ++r)
      p[(size_t)(mrow + r) * 64 + nb * 16 + col] = acc[nb][r];
}

// ---------------------------------------------------------------------------
// Fused reduce + rowwise. 256 blocks x 256 thr (4 waves).
__global__ __launch_bounds__(256) void k_rowtail(const float* __restrict__ part,
                                                 float* __restrict__ out,
                                                 int* __restrict__ cq,
                                                 float* __restrict__ psum,
                                                 float* __restrict__ lsqp,
                                                 int* __restrict__ gcount,
                                                 int* __restrict__ list,
                                                 int* __restrict__ flat) {
  __shared__ float tile[64][68];
  __shared__ float rmv[64], invv[64];
  __shared__ int   hist[64];
  const int bid  = blockIdx.x;
  const int tid  = threadIdx.x;
  const int wv   = tid >> 6;
  const int lane = tid & 63;
  const int t0   = bid * 64;
  if (tid < 64) hist[tid] = 0;

  {
    const size_t boff = (size_t)bid * 4096;
#pragma unroll
    for (int k = 0; k < 16; ++k) {
      int idx = k * 256 + tid;
      float v = part[boff + idx];
#pragma unroll
      for (int s = 1; s < NSPLIT; ++s) v += part[(size_t)s * PART_STRIDE + boff + idx];
      tile[idx >> 6][idx & 63] = v;
      out[O_LOGITS + boff + idx] = v;
    }
  }
  __syncthreads();

  // wave 1: per-row max, softmax denom, z-loss
  if (wv == 1) {
    const int r = lane;
    float rm = -3.0e38f;
#pragma unroll
    for (int c4 = 0; c4 < 16; ++c4) {
      float4 f = *(float4*)&tile[r][c4 * 4];
      rm = fmaxf(rm, fmaxf(fmaxf(f.x, f.y), fmaxf(f.z, f.w)));
    }
    float se = 0.0f;
#pragma unroll
    for (int c4 = 0; c4 < 16; ++c4) {
      float4 f = *(float4*)&tile[r][c4 * 4];
      se += expf(f.x - rm) + expf(f.y - rm) + expf(f.z - rm) + expf(f.w - rm);
    }
    rmv[r] = rm; invv[r] = 1.0f / se;
    float lse = rm + logf(se);
    float l2 = lse * lse;
#pragma unroll
    for (int o = 32; o > 0; o >>= 1) l2 += __shfl_down(l2, o);
    if (lane == 0) lsqp[bid] = l2;
  }
  __syncthreads();

  if (wv == 0) {
    // top-9 stable insertion on clipped keys + flag near-ties
    const unsigned t = t0 + lane;
    float val[9]; int idx[9];
#pragma unroll
    for (int j = 0; j < 9; ++j) { val[j] = -3.0e38f; idx[j] = 0; }
    bool flag = false;
#pragma unroll
    for (int c4 = 0; c4 < 16; ++c4) {
      float4 f = *(float4*)&tile[lane][c4 * 4];
      float fe[4] = {f.x, f.y, f.z, f.w};
#pragma unroll
      for (int jj = 0; jj < 4; ++jj) {
        float v = fe[jj];
        flag = flag || (fabsf(fabsf(v) - 2.0f) < EPS);
        float c = fminf(fmaxf(v, -2.0f), 2.0f);
        int id = c4 * 4 + jj;
#pragma unroll
        for (int j = 0; j < 9; ++j) {
          bool sw = c > val[j];
          float tv = sw ? val[j] : c; int ti = sw ? idx[j] : id;
          val[j] = sw ? c : val[j];   idx[j] = sw ? id : idx[j];
          c = tv; id = ti;
        }
      }
    }
#pragma unroll
    for (int j = 0; j < 8; ++j) {
      float gap = val[j] - val[j + 1];
      bool bothclip = (val[j] == val[j + 1]) && (fabsf(val[j]) == 2.0f);
      flag = flag || (gap < EPS && !bothclip);
    }
    if (!flag) {
      float m = val[0], pe[8], sum = 0.0f;
#pragma unroll
      for (int j = 0; j < 8; ++j) { pe[j] = expf(val[j] - m); sum += pe[j]; }
      float inv = 1.0f / sum;
      *(float4*)&out[O_PROBS + (size_t)t * 8]     = make_float4(pe[0]*inv, pe[1]*inv, pe[2]*inv, pe[3]*inv);
      *(float4*)&out[O_PROBS + (size_t)t * 8 + 4] = make_float4(pe[4]*inv, pe[5]*inv, pe[6]*inv, pe[7]*inv);
      *(float4*)&out[O_TIDX + (size_t)t * 8]      = make_float4((float)idx[0], (float)idx[1], (float)idx[2], (float)idx[3]);
      *(float4*)&out[O_TIDX + (size_t)t * 8 + 4]  = make_float4((float)idx[4], (float)idx[5], (float)idx[6], (float)idx[7]);
      *(int4*)&flat[(size_t)t * 8]     = make_int4(idx[0], idx[1], idx[2], idx[3]);
      *(int4*)&flat[(size_t)t * 8 + 4] = make_int4(idx[4], idx[5], idx[6], idx[7]);
#pragma unroll
      for (int j = 0; j < 8; ++j) atomicAdd(&hist[idx[j]], 1);
    } else {
      int sl = atomicAdd(gcount, 1);
      list[sl] = (int)t;
    }
  } else if (wv == 2 || wv == 3) {
    // softmax column half-sums (deterministic per-block partials)
    const int e = lane, half = wv - 2;
    float s = 0.0f;
#pragma unroll
    for (int r = 0; r < 32; ++r) {
      int rr = half * 32 + r;
      s += expf(tile[rr][e] - rmv[rr]) * invv[rr];
    }
    psum[(size_t)bid * 128 + half * 64 + e] = s;
  }
  __syncthreads();
  if (tid < 64) atomicAdd(&cq[(bid >> 5) * 64 + tid], hist[tid]);
}

// ---------------------------------------------------------------------------
// Exact f64 repair of flagged rows.
__global__ __launch_bounds__(256) void k_repair(const float* __restrict__ x,
                                                const float* __restrict__ w,
                                                const int* __restrict__ list,
                                                const int* __restrict__ gcount,
                                                float* __restrict__ out,
                                                int* __restrict__ cq,
                                                int* __restrict__ flat) {
  __shared__ double sh[4][64];
  __shared__ double tot[64];
  const int tid = threadIdx.x;
  const int wave = tid >> 6, lane = tid & 63;
  const int n = *gcount;
  for (int i = blockIdx.x; i < n; i += 256) {
    const int row = list[i];
    const float* xr = x + (size_t)row * HID;
    const float* wr = w + (size_t)lane * HID;
    double p0 = 0.0, p1 = 0.0, p2 = 0.0, p3 = 0.0;
    const int kb = wave * 1024;
    for (int k = kb; k < kb + 1024; k += 4) {
      float4 xv = *(const float4*)&xr[k];
      float4 wv = *(const float4*)&wr[k];
      p0 = fma((double)xv.x, (double)wv.x, p0);
      p1 = fma((double)xv.y, (double)wv.y, p1);
      p2 = fma((double)xv.z, (double)wv.z, p2);
      p3 = fma((double)xv.w, (double)wv.w, p3);
    }
    sh[wave][lane] = (p0 + p1) + (p2 + p3);
    __syncthreads();
    if (wave == 0) tot[lane] = (sh[0][lane] + sh[1][lane]) + (sh[2][lane] + sh[3][lane]);
    __syncthreads();
    if (tid == 0) {
      double val[8]; int idx[8];
#pragma unroll
      for (int j = 0; j < 8; ++j) { val[j] = -1.0e300; idx[j] = 0; }
      for (int e = 0; e < 64; ++e) {
        double c = fmin(fmax(tot[e], -2.0), 2.0);
        int id = e;
#pragma unroll
        for (int j = 0; j < 8; ++j) {
          bool sw = c > val[j];
          double tv = sw ? val[j] : c; int ti = sw ? idx[j] : id;
          val[j] = sw ? c : val[j];    idx[j] = sw ? id : idx[j];
          c = tv; id = ti;
        }
      }
      float m = (float)val[0], pe[8], sum = 0.0f;
#pragma unroll
      for (int j = 0; j < 8; ++j) { pe[j] = expf((float)val[j] - m); sum += pe[j]; }
      float inv = 1.0f / sum;
      const int q = row >> 11;
#pragma unroll
      for (int j = 0; j < 8; ++j) {
        out[O_PROBS + (size_t)row * 8 + j] = pe[j] * inv;
        out[O_TIDX  + (size_t)row * 8 + j] = (float)idx[j];
        flat[(size_t)row * 8 + j] = idx[j];
        atomicAdd(&cq[q * 64 + idx[j]], 1);
      }
    }
    __syncthreads();
  }
}

// ---------------------------------------------------------------------------
// cumsum/offsets + lb/z losses. 1 block x 256 threads.
__global__ __launch_bounds__(256) void k_final(const int* __restrict__ cq,
                                               const float* __restrict__ psum,
                                               const float* __restrict__ lsqp,
                                               float* __restrict__ out,
                                               int* __restrict__ offs2) {
  __shared__ int   ctot[64];
  __shared__ float gsum[4][64];
  const int tid = threadIdx.x;
  const int e = tid & 63, g = tid >> 6;

  if (tid < 64) {
    int tpe = 0;
#pragma unroll
    for (int q = 0; q < 8; ++q) tpe += cq[q * 64 + tid];
    ctot[tid] = tpe;
  }
  float ps = 0.0f;
  for (int b = g; b < 256; b += 4) ps += psum[(size_t)b * 128 + e] + psum[(size_t)b * 128 + 64 + e];
  gsum[g][e] = ps;
  __syncthreads();

  if (tid < 64) {
    int incl = 0;
    for (int i = 0; i <= tid; ++i) incl += ctot[i];
    int tpe = ctot[tid];
    out[O_TPE + tid]   = (float)tpe;
    out[O_GROUP + tid] = (float)incl;
    int o = incl - tpe;
#pragma unroll
    for (int q = 0; q < 8; ++q) { offs2[tid * 8 + q] = o; o += cq[q * 64 + tid]; }

    float pst = (gsum[0][tid] + gsum[1][tid]) + (gsum[2][tid] + gsum[3][tid]);
    float term = ((float)tpe / 131072.0f) * (pst / 16384.0f) * 64.0f;
#pragma unroll
    for (int o2 = 32; o2 > 0; o2 >>= 1) term += __shfl_down(term, o2);
    float zs = (lsqp[tid * 4] + lsqp[tid * 4 + 1]) + (lsqp[tid * 4 + 2] + lsqp[tid * 4 + 3]);
#pragma unroll
    for (int o2 = 32; o2 > 0; o2 >>= 1) zs += __shfl_down(zs, o2);
    if (tid == 0) { out[O_LB] = term; out[O_ZL] = zs / 16384.0f; }
  }
}

// ---------------------------------------------------------------------------
// Stable counting-sort scatter, split 8x by row-eighth: 512 blocks.
__global__ __launch_bounds__(256) void k_dispatch(const int* __restrict__ flat,
                                                  const int* __restrict__ offs2,
                                                  float* __restrict__ out) {
  __shared__ int wcs[4];
  const int e = blockIdx.x >> 3;
  const int q = blockIdx.x & 7;
  const int tid = threadIdx.x;
  const int lane = tid & 63;
  const int wv = tid >> 6;
  int base = offs2[e * 8 + q];
  const int seg0 = q * 16384;
  for (int c0 = 0; c0 < 16384; c0 += 2048) {
    const int j0 = seg0 + c0 + tid * 8;
    const int4* f4 = reinterpret_cast<const int4*>(flat + j0);
    int4 a = f4[0], b = f4[1];
    int v[8] = {a.x, a.y, a.z, a.w, b.x, b.y, b.z, b.w};
    int mcnt = 0;
#pragma unroll
    for (int k = 0; k < 8; ++k) mcnt += (v[k] == e) ? 1 : 0;
    int sc = mcnt;
#pragma unroll
    for (int o = 1; o < 64; o <<= 1) {
      int nn = __shfl_up(sc, o);
      if (lane >= o) sc += nn;
    }
    int excl = sc - mcnt;
    if (lane == 63) wcs[wv] = sc;
    __syncthreads();
    int woff = 0, tot = 0;
#pragma unroll
    for (int i = 0; i < 4; ++i) { int ci = wcs[i]; woff += (i < wv) ? ci : 0; tot += ci; }
    int pos = base + woff + excl;
#pragma unroll
    for (int k = 0; k < 8; ++k) {
      if (v[k] == e) { out[O_IDX + pos] = (float)(j0 + k); pos++; }
    }
    base += tot;
    __syncthreads();
  }
}

// ---------------------------------------------------------------------------
extern "C" void kernel_launch(void* const* d_in, const int* in_sizes, int n_in,
                              void* d_out, int out_size, void* d_ws, size_t ws_size,
                              hipStream_t stream) {
  (void)in_sizes; (void)n_in; (void)out_size; (void)ws_size;
  const float* x  = (const float*)d_in[0];
  const float* Wm = (const float*)d_in[1];
  float* out = (float*)d_out;
  char*  ws  = (char*)d_ws;

  int*    cq     = (int*)(ws + W_CQ);
  int*    gcount = (int*)(ws + W_GCOUNT);
  int*    offs2  = (int*)(ws + W_OFFS2);
  float*  lsqp   = (float*)(ws + W_LSQP);
  int*    list   = (int*)(ws + W_LIST);
  float*  psum   = (float*)(ws + W_PSUM);
  int*    flat   = (int*)(ws + W_FLAT);
  short8* wf     = (short8*)(ws + W_WF);
  float*  part   = (float*)(ws + W_PART);

  k_prep    <<<dim3(128), dim3(256), 0, stream>>>(Wm, wf, cq, gcount);
  // TIMING PROBE: k_gemm launched 3x (deterministic, atomics-free, idempotent).
  // T_gemm = (total_dur - 169.7us) / 2.
  k_gemm    <<<dim3(NTOK / 64, NSPLIT), dim3(256), 0, stream>>>(x, wf, part);
  k_gemm    <<<dim3(NTOK / 64, NSPLIT), dim3(256), 0, stream>>>(x, wf, part);
  k_gemm    <<<dim3(NTOK / 64, NSPLIT), dim3(256), 0, stream>>>(x, wf, part);
  k_rowtail <<<dim3(256), dim3(256), 0, stream>>>(part, out, cq, psum, lsqp, gcount, list, flat);
  k_repair  <<<dim3(256), dim3(256), 0, stream>>>(x, Wm, list, gcount, out, cq, flat);
  k_final   <<<dim3(1),   dim3(256), 0, stream>>>(cq, psum, lsqp, out, offs2);
  k_dispatch<<<dim3(512), dim3(256), 0, stream>>>(flat, offs2, out);
}

// Round 15
// 155.487 us; speedup vs baseline: 1.8095x; 1.8095x over previous
//
#include <hip/hip_runtime.h>
#include <hip/hip_bf16.h>
#include <math.h>

#define NTOK   16384
#define NEXP   64
#define HID    4096
#define KSEL   8
#define EPS    7.5e-5f
#define NSPLIT 4
#define KSZ    (HID / NSPLIT)

typedef __attribute__((ext_vector_type(8))) short short8;
typedef __attribute__((ext_vector_type(4))) float f32x4;

// d_out element offsets (f32 elements; int outputs stored as float values)
#define O_LOGITS 0u
#define O_PROBS  1048576u
#define O_TIDX   1179648u
#define O_GROUP  1310720u
#define O_IDX    1310784u
#define O_TPE    1441856u
#define O_LB     1441920u
#define O_ZL     1441921u

// ws byte offsets
#define W_CQ      0u          // 512 int: counts[q][e], q = row>>11
#define W_LSQP    8192u       // 256 f32 per-block z-loss partials
#define W_PSUM    81920u      // 256*128 f32 per-block half-tile probsum partials
#define W_FLAT    262144u     // 131072 int
#define W_WF      1048576u    // 1 MB: W packed as MFMA B-frags bf16 hi/lo
#define W_PART    2097152u    // NSPLIT x 4 MB f32 partials
#define PART_STRIDE 1048576ull

// round-to-nearest-even f32 -> bf16 bits
__device__ __forceinline__ unsigned short f2bf(float f) {
  unsigned u = __float_as_uint(f);
  return (unsigned short)((u + 0x7fffu + ((u >> 16) & 1u)) >> 16);
}

__device__ __forceinline__ void gload16(const void* g, void* l) {
  __builtin_amdgcn_global_load_lds((const __attribute__((address_space(1))) unsigned int*)g,
                                   (__attribute__((address_space(3))) unsigned int*)l, 16, 0, 0);
}

// ---------------------------------------------------------------------------
// prep: pack W into MFMA B-frags (bf16 hi/lo) + zero counters.
__global__ __launch_bounds__(256) void k_prep(const float* __restrict__ w,
                                              short8* __restrict__ wf,
                                              int* __restrict__ cq) {
  const int kk   = blockIdx.x;
  const int nb   = threadIdx.x >> 6;
  const int lane = threadIdx.x & 63;
  const int n    = nb * 16 + (lane & 15);
  const int kb   = kk * 32 + (lane >> 4) * 8;
  const float4* wp = (const float4*)(w + (size_t)n * HID + kb);
  float4 f0 = wp[0], f1 = wp[1];
  float fv[8] = {f0.x, f0.y, f0.z, f0.w, f1.x, f1.y, f1.z, f1.w};
  short8 hi, lo;
#pragma unroll
  for (int j = 0; j < 8; ++j) {
    unsigned short h = f2bf(fv[j]);
    hi[j] = (short)h;
    float r = fv[j] - __uint_as_float((unsigned)h << 16);
    lo[j] = (short)f2bf(r);
  }
  size_t base = ((size_t)(kk * 4 + nb) * 2) * 64 + lane;
  wf[base] = hi;
  wf[base + 64] = lo;
  if (blockIdx.x == 0) {
    cq[threadIdx.x] = 0;
    cq[threadIdx.x + 256] = 0;
  }
}

// ---------------------------------------------------------------------------
// MFMA router GEMM (R8-exact, measured 56us). wf LDS-shared (double-buffered,
// global_load_lds w16); x per-lane direct loads; one __syncthreads per chunk.
__global__ __launch_bounds__(256, 4) void k_gemm(const float* __restrict__ x,
                                                 const short8* __restrict__ wf,
                                                 float* __restrict__ part) {
  __shared__ short8 wl[2][512];   // 2 x 8 KB
  const int tid  = threadIdx.x;
  const int wv   = tid >> 6;
  const int lane = tid & 63;
  const int t0   = blockIdx.x * 64;
  const int k0   = blockIdx.y * KSZ;
  const int row  = t0 + wv * 16 + (lane & 15);

  const float* xp = x + (size_t)row * HID + k0 + (lane >> 4) * 8;
  const short8* wbase = wf + (size_t)(k0 >> 5) * 512;

  auto stage = [&](int c, int b) {
    const short8* src = wbase + (size_t)c * 512;
#pragma unroll
    for (int r = 0; r < 2; ++r) {
      const int o = r * 256 + wv * 64;       // wave-uniform LDS base
      gload16(src + o + lane, &wl[b][o]);    // lane*16B added by HW
    }
  };

  f32x4 acc[4] = {{0,0,0,0},{0,0,0,0},{0,0,0,0},{0,0,0,0}};

  stage(0, 0);
  __syncthreads();
  const int nch = KSZ >> 5;   // 32
  for (int c = 0; c < nch; ++c) {
    const int b = c & 1;
    if (c + 1 < nch) stage(c + 1, b ^ 1);

    const float4* xq = (const float4*)(xp + c * 32);
    float4 f0 = xq[0], f1 = xq[1];
    unsigned xb[8] = {__float_as_uint(f0.x), __float_as_uint(f0.y),
                      __float_as_uint(f0.z), __float_as_uint(f0.w),
                      __float_as_uint(f1.x), __float_as_uint(f1.y),
                      __float_as_uint(f1.z), __float_as_uint(f1.w)};
    union { unsigned u[4]; short8 s; } ua, ul;
#pragma unroll
    for (int p = 0; p < 4; ++p) {
      unsigned b0 = xb[2 * p], b1 = xb[2 * p + 1];
      ua.u[p] = __builtin_amdgcn_perm(b1, b0, 0x07060302u);
      float r0 = __uint_as_float(b0) - __uint_as_float(b0 & 0xffff0000u);
      float r1 = __uint_as_float(b1) - __uint_as_float(b1 & 0xffff0000u);
      unsigned t0b = __float_as_uint(r0), t1b = __float_as_uint(r1);
      t0b += 0x7fffu + ((t0b >> 16) & 1u);
      t1b += 0x7fffu + ((t1b >> 16) & 1u);
      ul.u[p] = __builtin_amdgcn_perm(t1b, t0b, 0x07060302u);
    }
    short8 ah = ua.s, al = ul.s;

#pragma unroll
    for (int nb = 0; nb < 4; ++nb) {
      short8 bh = wl[b][nb * 128 + lane];
      short8 bl = wl[b][nb * 128 + 64 + lane];
      acc[nb] = __builtin_amdgcn_mfma_f32_16x16x32_bf16(ah, bh, acc[nb], 0, 0, 0);
      acc[nb] = __builtin_amdgcn_mfma_f32_16x16x32_bf16(al, bh, acc[nb], 0, 0, 0);
      acc[nb] = __builtin_amdgcn_mfma_f32_16x16x32_bf16(ah, bl, acc[nb], 0, 0, 0);
    }
    __syncthreads();
  }

  float* p = part + (size_t)blockIdx.y * PART_STRIDE;
  const int mrow = t0 + wv * 16 + (lane >> 4) * 4;
  const int col  = lane & 15;
#pragma unroll
  for (int nb = 0; nb < 4; ++nb)
#pragma unroll
    for (int r = 0; r < 4; ++r)
      p[(size_t)(mrow + r) * 64 + nb * 16 + col] = acc[nb][r];
}

// ---------------------------------------------------------------------------
// Fused reduce + rowwise + IN-BLOCK candidate-limited exact repair.
// 256 blocks x 256 thr (4 waves). Flagged rows are block-local: candidates
// (clip(approx) >= val8 - 3*EPS, enumerated via ballot in index order) get
// exact f64 dots (64-lane split + f64 shuffle reduce); top-8 selected among
// candidates only (provably identical to full f64 repair).
__global__ __launch_bounds__(256) void k_rowtail(const float* __restrict__ part,
                                                 const float* __restrict__ x,
                                                 const float* __restrict__ w,
                                                 float* __restrict__ out,
                                                 int* __restrict__ cq,
                                                 float* __restrict__ psum,
                                                 float* __restrict__ lsqp,
                                                 int* __restrict__ flat) {
  __shared__ float tile[64][68];
  __shared__ float rmv[64], invv[64], val8s[64];
  __shared__ int   hist[64];
  __shared__ int   fl_rows[64];
  __shared__ int   fl_n;
  __shared__ unsigned long long candmask;
  __shared__ double cexact[64];
  const int bid  = blockIdx.x;
  const int tid  = threadIdx.x;
  const int wv   = tid >> 6;
  const int lane = tid & 63;
  const int t0   = bid * 64;
  if (tid < 64) hist[tid] = 0;
  if (tid == 0) fl_n = 0;

  {
    const size_t boff = (size_t)bid * 4096;
#pragma unroll
    for (int k = 0; k < 16; ++k) {
      int idx = k * 256 + tid;
      float v = part[boff + idx];
#pragma unroll
      for (int s = 1; s < NSPLIT; ++s) v += part[(size_t)s * PART_STRIDE + boff + idx];
      tile[idx >> 6][idx & 63] = v;
      out[O_LOGITS + boff + idx] = v;
    }
  }
  __syncthreads();

  // wave 1: per-row max, softmax denom, z-loss
  if (wv == 1) {
    const int r = lane;
    float rm = -3.0e38f;
#pragma unroll
    for (int c4 = 0; c4 < 16; ++c4) {
      float4 f = *(float4*)&tile[r][c4 * 4];
      rm = fmaxf(rm, fmaxf(fmaxf(f.x, f.y), fmaxf(f.z, f.w)));
    }
    float se = 0.0f;
#pragma unroll
    for (int c4 = 0; c4 < 16; ++c4) {
      float4 f = *(float4*)&tile[r][c4 * 4];
      se += expf(f.x - rm) + expf(f.y - rm) + expf(f.z - rm) + expf(f.w - rm);
    }
    rmv[r] = rm; invv[r] = 1.0f / se;
    float lse = rm + logf(se);
    float l2 = lse * lse;
#pragma unroll
    for (int o = 32; o > 0; o >>= 1) l2 += __shfl_down(l2, o);
    if (lane == 0) lsqp[bid] = l2;
  }
  __syncthreads();

  if (wv == 0) {
    // top-9 stable insertion on clipped keys + flag near-ties
    const unsigned t = t0 + lane;
    float val[9]; int idx[9];
#pragma unroll
    for (int j = 0; j < 9; ++j) { val[j] = -3.0e38f; idx[j] = 0; }
    bool flag = false;
#pragma unroll
    for (int c4 = 0; c4 < 16; ++c4) {
      float4 f = *(float4*)&tile[lane][c4 * 4];
      float fe[4] = {f.x, f.y, f.z, f.w};
#pragma unroll
      for (int jj = 0; jj < 4; ++jj) {
        float v = fe[jj];
        flag = flag || (fabsf(fabsf(v) - 2.0f) < EPS);
        float c = fminf(fmaxf(v, -2.0f), 2.0f);
        int id = c4 * 4 + jj;
#pragma unroll
        for (int j = 0; j < 9; ++j) {
          bool sw = c > val[j];
          float tv = sw ? val[j] : c; int ti = sw ? idx[j] : id;
          val[j] = sw ? c : val[j];   idx[j] = sw ? id : idx[j];
          c = tv; id = ti;
        }
      }
    }
    val8s[lane] = val[8];
#pragma unroll
    for (int j = 0; j < 8; ++j) {
      float gap = val[j] - val[j + 1];
      bool bothclip = (val[j] == val[j + 1]) && (fabsf(val[j]) == 2.0f);
      flag = flag || (gap < EPS && !bothclip);
    }
    if (!flag) {
      float m = val[0], pe[8], sum = 0.0f;
#pragma unroll
      for (int j = 0; j < 8; ++j) { pe[j] = expf(val[j] - m); sum += pe[j]; }
      float inv = 1.0f / sum;
      *(float4*)&out[O_PROBS + (size_t)t * 8]     = make_float4(pe[0]*inv, pe[1]*inv, pe[2]*inv, pe[3]*inv);
      *(float4*)&out[O_PROBS + (size_t)t * 8 + 4] = make_float4(pe[4]*inv, pe[5]*inv, pe[6]*inv, pe[7]*inv);
      *(float4*)&out[O_TIDX + (size_t)t * 8]      = make_float4((float)idx[0], (float)idx[1], (float)idx[2], (float)idx[3]);
      *(float4*)&out[O_TIDX + (size_t)t * 8 + 4]  = make_float4((float)idx[4], (float)idx[5], (float)idx[6], (float)idx[7]);
      *(int4*)&flat[(size_t)t * 8]     = make_int4(idx[0], idx[1], idx[2], idx[3]);
      *(int4*)&flat[(size_t)t * 8 + 4] = make_int4(idx[4], idx[5], idx[6], idx[7]);
#pragma unroll
      for (int j = 0; j < 8; ++j) atomicAdd(&hist[idx[j]], 1);
    } else {
      int sl = atomicAdd(&fl_n, 1);
      fl_rows[sl] = lane;
    }
  } else if (wv == 2 || wv == 3) {
    // softmax column half-sums (deterministic per-block partials)
    const int e = lane, half = wv - 2;
    float s = 0.0f;
#pragma unroll
    for (int r = 0; r < 32; ++r) {
      int rr = half * 32 + r;
      s += expf(tile[rr][e] - rmv[rr]) * invv[rr];
    }
    psum[(size_t)bid * 128 + half * 64 + e] = s;
  }
  __syncthreads();

  // ---- in-block repair of flagged rows (candidate-limited exact f64) ----
  for (int i = 0; i < fl_n; ++i) {
    const int r = fl_rows[i];
    if (wv == 0) {
      float c = fminf(fmaxf(tile[r][lane], -2.0f), 2.0f);
      bool cnd = (c >= val8s[r] - 3.0f * EPS);
      unsigned long long m = __ballot(cnd);
      if (lane == 0) candmask = m;
    }
    __syncthreads();
    const unsigned long long m = candmask;
    const float* xr = x + (size_t)(t0 + r) * HID;
    {
      int ord = 0;
      for (int e = 0; e < 64; ++e) {
        if ((m >> e) & 1ull) {
          if ((ord & 3) == wv) {
            const float* wr = w + (size_t)e * HID;
            double p0 = 0.0, p1 = 0.0, p2 = 0.0, p3 = 0.0;
            const int kb = lane * 64;
            for (int k = kb; k < kb + 64; k += 4) {
              float4 xv = *(const float4*)&xr[k];
              float4 wv4 = *(const float4*)&wr[k];
              p0 = fma((double)xv.x, (double)wv4.x, p0);
              p1 = fma((double)xv.y, (double)wv4.y, p1);
              p2 = fma((double)xv.z, (double)wv4.z, p2);
              p3 = fma((double)xv.w, (double)wv4.w, p3);
            }
            double p = (p0 + p1) + (p2 + p3);
#pragma unroll
            for (int o = 32; o > 0; o >>= 1) p += __shfl_down(p, o);
            if (lane == 0) cexact[e] = fmin(fmax(p, -2.0), 2.0);
          }
          ord++;
        }
      }
    }
    __syncthreads();
    if (tid == r) {   // row owner: stable top-8 among candidates (ascending e)
      double val[8]; int idx[8];
#pragma unroll
      for (int j = 0; j < 8; ++j) { val[j] = -1.0e300; idx[j] = 0; }
      for (int e = 0; e < 64; ++e) {
        if (!((m >> e) & 1ull)) continue;
        double c = cexact[e];
        int id = e;
#pragma unroll
        for (int j = 0; j < 8; ++j) {
          bool sw = c > val[j];
          double tv = sw ? val[j] : c; int ti = sw ? idx[j] : id;
          val[j] = sw ? c : val[j];    idx[j] = sw ? id : idx[j];
          c = tv; id = ti;
        }
      }
      float mm = (float)val[0], pe[8], sum = 0.0f;
#pragma unroll
      for (int j = 0; j < 8; ++j) { pe[j] = expf((float)val[j] - mm); sum += pe[j]; }
      float inv = 1.0f / sum;
      const unsigned t = t0 + r;
#pragma unroll
      for (int j = 0; j < 8; ++j) {
        out[O_PROBS + (size_t)t * 8 + j] = pe[j] * inv;
        out[O_TIDX  + (size_t)t * 8 + j] = (float)idx[j];
        flat[(size_t)t * 8 + j] = idx[j];
        atomicAdd(&hist[idx[j]], 1);
      }
    }
    __syncthreads();
  }

  if (tid < 64) atomicAdd(&cq[(bid >> 5) * 64 + tid], hist[tid]);
}

// ---------------------------------------------------------------------------
// Stable counting-sort scatter + inlined finalize. 512 blocks x 256 thr.
// Each block recomputes its own base offset from cq; block 0 additionally
// emits tokens_per_expert / group_indices / lb_loss / z_loss.
__global__ __launch_bounds__(256) void k_dispatch(const int* __restrict__ flat,
                                                  const int* __restrict__ cq,
                                                  const float* __restrict__ psum,
                                                  const float* __restrict__ lsqp,
                                                  float* __restrict__ out) {
  __shared__ int ctot[64];
  __shared__ int sbase;
  __shared__ int wcs[4];
  __shared__ float gsum[4][64];
  const int e = blockIdx.x >> 3;
  const int q = blockIdx.x & 7;
  const int tid = threadIdx.x;
  const int lane = tid & 63;
  const int wv = tid >> 6;

  if (tid < 64) {
    int tpe = 0;
#pragma unroll
    for (int qq = 0; qq < 8; ++qq) tpe += cq[qq * 64 + tid];
    ctot[tid] = tpe;
  }
  __syncthreads();
  if (tid == 0) {
    int b = 0;
    for (int i = 0; i < e; ++i) b += ctot[i];
    for (int qq = 0; qq < q; ++qq) b += cq[qq * 64 + e];
    sbase = b;
  }

  // block 0: finalize (tpe/group/lb/zl) while others proceed
  if (blockIdx.x == 0) {
    const int e2 = tid & 63, g = tid >> 6;
    float ps = 0.0f;
    for (int b = g; b < 256; b += 4) ps += psum[(size_t)b * 128 + e2] + psum[(size_t)b * 128 + 64 + e2];
    gsum[g][e2] = ps;
    __syncthreads();
    if (tid < 64) {
      int incl = 0;
      for (int i = 0; i <= tid; ++i) incl += ctot[i];
      int tpe = ctot[tid];
      out[O_TPE + tid]   = (float)tpe;
      out[O_GROUP + tid] = (float)incl;
      float pst = (gsum[0][tid] + gsum[1][tid]) + (gsum[2][tid] + gsum[3][tid]);
      float term = ((float)tpe / 131072.0f) * (pst / 16384.0f) * 64.0f;
#pragma unroll
      for (int o2 = 32; o2 > 0; o2 >>= 1) term += __shfl_down(term, o2);
      float zs = (lsqp[tid * 4] + lsqp[tid * 4 + 1]) + (lsqp[tid * 4 + 2] + lsqp[tid * 4 + 3]);
#pragma unroll
      for (int o2 = 32; o2 > 0; o2 >>= 1) zs += __shfl_down(zs, o2);
      if (tid == 0) { out[O_LB] = term; out[O_ZL] = zs / 16384.0f; }
    }
  }
  __syncthreads();

  int base = sbase;
  const int seg0 = q * 16384;
  for (int c0 = 0; c0 < 16384; c0 += 2048) {
    const int j0 = seg0 + c0 + tid * 8;
    const int4* f4 = reinterpret_cast<const int4*>(flat + j0);
    int4 a = f4[0], b = f4[1];
    int v[8] = {a.x, a.y, a.z, a.w, b.x, b.y, b.z, b.w};
    int mcnt = 0;
#pragma unroll
    for (int k = 0; k < 8; ++k) mcnt += (v[k] == e) ? 1 : 0;
    int sc = mcnt;
#pragma unroll
    for (int o = 1; o < 64; o <<= 1) {
      int nn = __shfl_up(sc, o);
      if (lane >= o) sc += nn;
    }
    int excl = sc - mcnt;
    if (lane == 63) wcs[wv] = sc;
    __syncthreads();
    int woff = 0, tot = 0;
#pragma unroll
    for (int i = 0; i < 4; ++i) { int ci = wcs[i]; woff += (i < wv) ? ci : 0; tot += ci; }
    int pos = base + woff + excl;
#pragma unroll
    for (int k = 0; k < 8; ++k) {
      if (v[k] == e) { out[O_IDX + pos] = (float)(j0 + k); pos++; }
    }
    base += tot;
    __syncthreads();
  }
}

// ---------------------------------------------------------------------------
extern "C" void kernel_launch(void* const* d_in, const int* in_sizes, int n_in,
                              void* d_out, int out_size, void* d_ws, size_t ws_size,
                              hipStream_t stream) {
  (void)in_sizes; (void)n_in; (void)out_size; (void)ws_size;
  const float* x  = (const float*)d_in[0];
  const float* Wm = (const float*)d_in[1];
  float* out = (float*)d_out;
  char*  ws  = (char*)d_ws;

  int*    cq     = (int*)(ws + W_CQ);
  float*  lsqp   = (float*)(ws + W_LSQP);
  float*  psum   = (float*)(ws + W_PSUM);
  int*    flat   = (int*)(ws + W_FLAT);
  short8* wf     = (short8*)(ws + W_WF);
  float*  part   = (float*)(ws + W_PART);

  k_prep    <<<dim3(128), dim3(256), 0, stream>>>(Wm, wf, cq);
  k_gemm    <<<dim3(NTOK / 64, NSPLIT), dim3(256), 0, stream>>>(x, wf, part);
  k_rowtail <<<dim3(256), dim3(256), 0, stream>>>(part, x, Wm, out, cq, psum, lsqp, flat);
  k_dispatch<<<dim3(512), dim3(256), 0, stream>>>(flat, cq, psum, lsqp, out);
}